// Round 13
// baseline (73.892 us; speedup 1.0000x reference)
//
#include <hip/hip_runtime.h>
#include <hip/hip_bf16.h>

// y = softmax_causal((x Wq^T)(x Wk^T)^T / 8) (x Wv^T)
// B=4, S=4096, D_EMBED=1024, D=64. fp32 in/out; bf16 MFMA compute.

typedef short s16x8 __attribute__((ext_vector_type(8)));
typedef float f32x4 __attribute__((ext_vector_type(4)));
typedef float f32x16 __attribute__((ext_vector_type(16)));
typedef unsigned u32x2 __attribute__((ext_vector_type(2)));
typedef union { unsigned u[4]; s16x8 v; } pfrag;

#define MFMA16(a, b, c) __builtin_amdgcn_mfma_f32_16x16x32_bf16(a, b, c, 0, 0, 0)
#define MFMA32(a, b, c) __builtin_amdgcn_mfma_f32_32x32x16_bf16(a, b, c, 0, 0, 0)

constexpr int SEQ = 4096;
constexpr int DE  = 1024;

__device__ __forceinline__ short f2bf(float f) {            // RNE fp32->bf16
    union { float f; unsigned u; } v; v.f = f;
    unsigned r = (v.u + 0x7FFFu + ((v.u >> 16) & 1u)) >> 16;
    return (short)r;
}
__device__ __forceinline__ unsigned fbits(float f) { union { float f; unsigned u; } v; v.f = f; return v.u; }
__device__ __forceinline__ float bitsf(unsigned u) { union { unsigned u; float f; } v; v.u = u; return v.f; }
__device__ __forceinline__ unsigned pk2(float a, float b) {  // 2xf32 -> packed bf16 (trunc)
    return (fbits(b) & 0xFFFF0000u) | (fbits(a) >> 16);
}

#define GLDS(gp, lp)                                                          \
    __builtin_amdgcn_global_load_lds(                                         \
        (const __attribute__((address_space(1))) unsigned int*)(gp),          \
        (__attribute__((address_space(3))) unsigned int*)(lp), 16, 0, 0)

// ---------------------------------------------------------------------------
// Kernel 0: W (fp32 [64][1024] x3) -> bf16 [192][1024]; 0.125*log2e folded in Wq.
__global__ __launch_bounds__(256) void k_convw(const float* __restrict__ Wq,
                                               const float* __restrict__ Wk,
                                               const float* __restrict__ Wv,
                                               short* __restrict__ Wb) {
    int i = (blockIdx.x * 256 + threadIdx.x) * 4;
    if (i >= 192 * 1024) return;
    int n = i >> 10, k = i & 1023;
    const float* src; float sc;
    if (n < 64)       { src = Wq + n * 1024;         sc = 0.18033688011112042f; }
    else if (n < 128) { src = Wk + (n - 64) * 1024;  sc = 1.0f; }
    else              { src = Wv + (n - 128) * 1024; sc = 1.0f; }
    float4 v = *(const float4*)(src + k);
    short4 o;
    o.x = f2bf(v.x * sc); o.y = f2bf(v.y * sc);
    o.z = f2bf(v.z * sc); o.w = f2bf(v.w * sc);
    *(short4*)(Wb + i) = o;
}

// ---------------------------------------------------------------------------
// Kernel 1: QKV projection, BM=32 / 512 blocks (2 blocks/CU resident ->
// 16 waves/CU). Per K-step: A 8KB (1 GLDS/thr) + W 24KB (3 GLDS/thr), vmcnt(4).
__global__ __launch_bounds__(512, 4) void k_proj(const float* __restrict__ x,
                                                 const short* __restrict__ Wb,
                                                 short* __restrict__ Qs,
                                                 short* __restrict__ Ks,
                                                 short* __restrict__ Vt) {
    __shared__ __align__(16) char lds[2][32768];   // per buf: A 8KB | W 24KB
    const int tid  = threadIdx.x;
    const int lane = tid & 63;
    const int c = lane & 15, g = (lane >> 4) & 3;
    const int wv = tid >> 6;
    const int rg = wv & 1, nh = wv >> 1;
    const int n0 = nh * 48;
    const int m0 = blockIdx.x * 32;

    const int Ar  = tid >> 4;                                   // A row 0..31
    const int Acs = ((tid & 15) << 4) ^ ((Ar & 7) << 4);
    const char* aS0 = (const char*)x + (((size_t)(m0 + Ar)) << 12) + Acs;
    const int Wr  = tid >> 3;                                   // W row 0..63
    const int Wcs = ((tid & 7) << 4) ^ ((Wr & 7) << 4);
    const char* wS0 = (const char*)Wb + (((size_t)Wr) << 11) + Wcs;
    const char* wS1 = wS0 + ((size_t)64 << 11);
    const char* wS2 = wS0 + ((size_t)128 << 11);

    char* db0 = &lds[0][0] + tid * 16;
    char* db1 = &lds[1][0] + tid * 16;

    const int arow = rg * 16 + c;
    const int swz  = (c & 7) << 4;
    const char* aR[2] = { &lds[0][0] + arow * 256, &lds[1][0] + arow * 256 };
    const char* wR[2][3];
#pragma unroll
    for (int nf = 0; nf < 3; nf++) {
        int wrow = n0 + nf * 16 + c;
        wR[0][nf] = &lds[0][0] + 8192 + wrow * 128;
        wR[1][nf] = &lds[1][0] + 8192 + wrow * 128;
    }

    f32x4 acc[3];
#pragma unroll
    for (int i = 0; i < 3; i++) acc[i] = (f32x4){0.f, 0.f, 0.f, 0.f};

#define PSTAGE(kk, db) {                                  \
        GLDS(aS0 + (kk) * 256, (db));                     \
        GLDS(wS0 + (kk) * 128, (db) + 8192);              \
        GLDS(wS1 + (kk) * 128, (db) + 16384);             \
        GLDS(wS2 + (kk) * 128, (db) + 24576); }

#define PCOMPUTE(bi) {                                                         \
        _Pragma("unroll")                                                      \
        for (int kc = 0; kc < 2; kc++) {                                       \
            float4 a0 = *(const float4*)(aR[bi] + ((kc*128 + g*32)      ^ swz)); \
            float4 a1 = *(const float4*)(aR[bi] + ((kc*128 + g*32 + 16) ^ swz)); \
            s16x8 a;                                                           \
            a[0]=f2bf(a0.x); a[1]=f2bf(a0.y); a[2]=f2bf(a0.z); a[3]=f2bf(a0.w); \
            a[4]=f2bf(a1.x); a[5]=f2bf(a1.y); a[6]=f2bf(a1.z); a[7]=f2bf(a1.w); \
            _Pragma("unroll")                                                  \
            for (int nf = 0; nf < 3; nf++) {                                   \
                s16x8 bfr = *(const s16x8*)(wR[bi][nf] + ((kc*64 + g*16) ^ swz)); \
                acc[nf] = MFMA16(a, bfr, acc[nf]);                             \
            }                                                                  \
        } }

    PSTAGE(0, db0);
    PSTAGE(1, db1);

    for (int kk = 0; kk < 15; kk++) {
        asm volatile("s_waitcnt vmcnt(4)" ::: "memory");
        __builtin_amdgcn_sched_barrier(0);
        __builtin_amdgcn_s_barrier();
        if (kk & 1) PCOMPUTE(1) else PCOMPUTE(0)
        asm volatile("s_waitcnt lgkmcnt(0)" ::: "memory");
        __builtin_amdgcn_sched_barrier(0);
        __builtin_amdgcn_s_barrier();
        if (kk < 14) { if (kk & 1) PSTAGE(kk + 2, db1) else PSTAGE(kk + 2, db0) }
    }
    asm volatile("s_waitcnt vmcnt(0)" ::: "memory");
    __builtin_amdgcn_sched_barrier(0);
    __builtin_amdgcn_s_barrier();
    PCOMPUTE(1)
#undef PSTAGE
#undef PCOMPUTE

#pragma unroll
    for (int nf = 0; nf < 3; nf++) {
        int col16 = n0 + nf * 16;
        if (col16 < 64) {
            int col = col16 + c;
#pragma unroll
            for (int r = 0; r < 4; r++)
                Qs[(size_t)(m0 + rg * 16 + g * 4 + r) * 64 + col] = f2bf(acc[nf][r]);
        } else if (col16 < 128) {
            int col = col16 - 64 + c;
#pragma unroll
            for (int r = 0; r < 4; r++)
                Ks[(size_t)(m0 + rg * 16 + g * 4 + r) * 64 + col] = f2bf(acc[nf][r]);
        } else {
            int d  = col16 - 128 + c;
            int mm = m0 + rg * 16 + g * 4;
            int bt = mm >> 12, s0 = mm & (SEQ - 1);
            short4 o;
            o.x = f2bf(acc[nf][0]); o.y = f2bf(acc[nf][1]);
            o.z = f2bf(acc[nf][2]); o.w = f2bf(acc[nf][3]);
            *(short4*)(Vt + ((size_t)(bt * 64 + d)) * SEQ + s0) = o;
        }
    }
}

// ---------------------------------------------------------------------------
#define PACKPH(sa, sb, u0, u1, u2, u3) {                                       \
    unsigned A0 = pk2(sa[0], sa[1]),   B0 = pk2(sa[2], sa[3]);                 \
    unsigned A1 = pk2(sa[4], sa[5]),   B1 = pk2(sa[6], sa[7]);                 \
    unsigned A2 = pk2(sa[8], sa[9]),   B2 = pk2(sa[10], sa[11]);               \
    unsigned A3 = pk2(sa[12], sa[13]), B3 = pk2(sa[14], sa[15]);               \
    u32x2 r0_ = __builtin_amdgcn_permlane32_swap(A0, A1, false, false);        \
    u32x2 r1_ = __builtin_amdgcn_permlane32_swap(B0, B1, false, false);        \
    u32x2 r2_ = __builtin_amdgcn_permlane32_swap(A2, A3, false, false);        \
    u32x2 r3_ = __builtin_amdgcn_permlane32_swap(B2, B3, false, false);        \
    u0.u[0] = r0_[0]; u0.u[1] = r1_[0]; u0.u[2] = r0_[1]; u0.u[3] = r1_[1];    \
    u1.u[0] = r2_[0]; u1.u[1] = r3_[0]; u1.u[2] = r2_[1]; u1.u[3] = r3_[1];    \
    A0 = pk2(sb[0], sb[1]);   B0 = pk2(sb[2], sb[3]);                          \
    A1 = pk2(sb[4], sb[5]);   B1 = pk2(sb[6], sb[7]);                          \
    A2 = pk2(sb[8], sb[9]);   B2 = pk2(sb[10], sb[11]);                        \
    A3 = pk2(sb[12], sb[13]); B3 = pk2(sb[14], sb[15]);                        \
    r0_ = __builtin_amdgcn_permlane32_swap(A0, A1, false, false);              \
    r1_ = __builtin_amdgcn_permlane32_swap(B0, B1, false, false);              \
    r2_ = __builtin_amdgcn_permlane32_swap(A2, A3, false, false);              \
    r3_ = __builtin_amdgcn_permlane32_swap(B2, B3, false, false);              \
    u2.u[0] = r0_[0]; u2.u[1] = r1_[0]; u2.u[2] = r0_[1]; u2.u[3] = r1_[1];    \
    u3.u[0] = r2_[0]; u3.u[1] = r3_[0]; u3.u[2] = r2_[1]; u3.u[3] = r3_[1]; }

// ---------------------------------------------------------------------------
// Kernel 2 (v8): occupancy-first. Units = (bt, 128q-tile j, 256-kv seg):
// nseg(j) = (j+2)>>1, 272 units/bt -> 1088 blocks x 4 waves = 4352 waves
// (17/CU, within the 5-block LDS cap, real backfill). GLDS 2-buf, vmcnt(4).
// No lgkm fence BEFORE compute (compiler overlaps ds_read latency with QK);
// fence only after compute (WAR before restage). Defer-max (T13) + setprio.
__global__ __launch_bounds__(256, 2) void k_attn(const short* __restrict__ Qs,
                                                 const short* __restrict__ Ks,
                                                 const short* __restrict__ Vt,
                                                 float* __restrict__ pws) {
    __shared__ __align__(16) char smem[2][16384];   // per buf: K 8KB | V 8KB

    int tid = threadIdx.x;
    int l = tid & 63, wv = tid >> 6;
    int q = l & 31, hi = l >> 5;

    // decode: heavy j first; nseg(j) = (j+2)>>1
    int ub = blockIdx.x >> 2, bt = blockIdx.x & 3;
    int u = ub, j = 31, cs = 16;
    while (u >= cs) { u -= cs; --j; cs = (j + 2) >> 1; }
    int seg = u;
    int kb0 = seg << 8;
    int kend_t = min(j * 128 + 128, kb0 + 256);
    const int R = (kend_t - kb0 + 63) >> 6;
    const int q0 = j * 128 + wv * 32;
    const int mycend = q0 + 32;

    const short* Qb = Qs + (size_t)bt * SEQ * 64;
    const short* Kb = Ks + (size_t)bt * SEQ * 64;
    const short* Vb = Vt + (size_t)bt * 64 * SEQ;

    s16x8 qf[4];
#pragma unroll
    for (int d = 0; d < 4; d++)
        qf[d] = *(const s16x8*)(Qb + (size_t)(q0 + q) * 64 + d * 16 + hi * 8);

    const int row8 = l >> 3;
    const int scs  = (l & 7) ^ row8;       // pre-XORed source chunk

#define ASTAGE(kb, b) {                                                        \
        _Pragma("unroll")                                                      \
        for (int i = 0; i < 2; i++) {                                          \
            GLDS(Kb + (((size_t)((kb) + wv*16 + i*8 + row8)) << 6) + scs*8,    \
                 &smem[b][0] + (wv*16 + i*8)*128);                             \
            GLDS(Vb + (size_t)(wv*16 + i*8 + row8) * SEQ + (kb) + scs*8,       \
                 &smem[b][0] + 8192 + (wv*16 + i*8)*128); } }

    f32x16 o0 = {}, o1 = {};
    float m = -1e30f, ll = 0.f;
    const int qs7 = q & 7;

    ASTAGE(kb0, 0);
    if (R > 1) ASTAGE(kb0 + 64, 1);

    for (int r = 0; r < R; r++) {
        if (r == R - 1) asm volatile("s_waitcnt vmcnt(0)" ::: "memory");
        else            asm volatile("s_waitcnt vmcnt(4)" ::: "memory");
        __builtin_amdgcn_sched_barrier(0);
        __builtin_amdgcn_s_barrier();        // slab r ready

        // ---- ds_reads + compute: compiler schedules lgkmcnt fine-grained ----
        const char* kl = &smem[r & 1][0];
        const char* vl = kl + 8192;
        s16x8 kf[8], vf[8];
#pragma unroll
        for (int dd = 0; dd < 4; dd++) {
            int ch = ((2 * dd + hi) ^ qs7) << 4;
            kf[dd]     = *(const s16x8*)(kl + q * 128 + ch);
            kf[4 + dd] = *(const s16x8*)(kl + (32 + q) * 128 + ch);
            vf[dd]     = *(const s16x8*)(vl + q * 128 + ch);
            vf[4 + dd] = *(const s16x8*)(vl + (32 + q) * 128 + ch);
        }

        int k0 = kb0 + r * 64;
        if (k0 < mycend) {
            f32x16 sa = {}, sb = {};
            __builtin_amdgcn_s_setprio(1);
#pragma unroll
            for (int dd = 0; dd < 4; dd++) {
                sa = MFMA32(kf[dd],     qf[dd], sa);
                sb = MFMA32(kf[4 + dd], qf[dd], sb);
            }
            __builtin_amdgcn_s_setprio(0);
            if (k0 + 31 > q0) {
#pragma unroll
                for (int rr = 0; rr < 16; rr++) {
                    int kv = k0 + (rr & 3) + 8 * (rr >> 2) + 4 * hi;
                    if (kv > q0 + q) sa[rr] = -3.0e38f;
                }
            }
            if (k0 + 63 > q0) {
#pragma unroll
                for (int rr = 0; rr < 16; rr++) {
                    int kv = k0 + 32 + (rr & 3) + 8 * (rr >> 2) + 4 * hi;
                    if (kv > q0 + q) sb[rr] = -3.0e38f;
                }
            }
            // ---- softmax with defer-max (THR = 8 in log2 units) ----
            float t0 = -3.0e38f, t1 = -3.0e38f;
#pragma unroll
            for (int rr = 0; rr < 16; rr++) { t0 = fmaxf(t0, sa[rr]); t1 = fmaxf(t1, sb[rr]); }
            float tm = fmaxf(t0, t1);
            u32x2 sw = __builtin_amdgcn_permlane32_swap(fbits(tm), fbits(tm), false, false);
            tm = fmaxf(bitsf(sw[0]), bitsf(sw[1]));
            if (__any(tm > m + 8.0f)) {
                float mn = fmaxf(m, tm);
                float sc_ = __builtin_amdgcn_exp2f(m - mn);
                m = mn;
                ll *= sc_;
                o0 *= sc_; o1 *= sc_;
            }
            float ss = 0.f;
#pragma unroll
            for (int rr = 0; rr < 16; rr++) {
                sa[rr] = __builtin_amdgcn_exp2f(sa[rr] - m);
                sb[rr] = __builtin_amdgcn_exp2f(sb[rr] - m);
                ss += sa[rr] + sb[rr];
            }
            sw = __builtin_amdgcn_permlane32_swap(fbits(ss), fbits(ss), false, false);
            ss = bitsf(sw[0]) + bitsf(sw[1]);
            ll += ss;

            pfrag u0_, u1_, u2_, u3_;
            PACKPH(sa, sb, u0_, u1_, u2_, u3_);
            __builtin_amdgcn_s_setprio(1);
            o0 = MFMA32(vf[0], u0_.v, o0);
            o0 = MFMA32(vf[1], u1_.v, o0);
            o0 = MFMA32(vf[2], u2_.v, o0);
            o0 = MFMA32(vf[3], u3_.v, o0);
            o1 = MFMA32(vf[4], u0_.v, o1);
            o1 = MFMA32(vf[5], u1_.v, o1);
            o1 = MFMA32(vf[6], u2_.v, o1);
            o1 = MFMA32(vf[7], u3_.v, o1);
            __builtin_amdgcn_s_setprio(0);
        }

        asm volatile("s_waitcnt lgkmcnt(0)" ::: "memory");  // my reads retired
        __builtin_amdgcn_sched_barrier(0);
        __builtin_amdgcn_s_barrier();        // slab r free for overwrite
        if (r + 2 < R) { if (r & 1) ASTAGE(kb0 + (r + 2) * 64, 1) else ASTAGE(kb0 + (r + 2) * 64, 0) }
    }
#undef ASTAGE

    // ---- per-wave partial (O^T, M, L) -> ws ----
    float* p = pws + ((((size_t)(bt * 32 + j) * 4 + wv) * 16 + seg)) * 2112;
#pragma unroll
    for (int rr = 0; rr < 16; rr++) {
        int dv = (rr & 3) + 8 * (rr >> 2) + 4 * hi;
        p[dv * 32 + q]        = o0[rr];
        p[(dv + 32) * 32 + q] = o1[rr];
    }
    if (hi == 0) { p[2048 + q] = m; p[2080 + q] = ll; }
}

// ---------------------------------------------------------------------------
// Kernel 3: merge <=16 segment partials per (bt, j, wave-sub) -> fp32 out.
__global__ __launch_bounds__(256) void k_comb(const float* __restrict__ pws,
                                              float* __restrict__ out) {
    int b = blockIdx.x;                      // bt*128 + j*4 + w
    int w = b & 3, j = (b >> 2) & 31, bt = b >> 7;
    int nseg = (j + 2) >> 1;

    int tid = threadIdx.x;
    int q = tid >> 3, dv0 = (tid & 7) * 8;
    const float* base = pws + ((size_t)(bt * 32 + j) * 4 + w) * 16 * 2112;

    float ms[16], wsg[16];
    float M = -1e30f;
#pragma unroll
    for (int s = 0; s < 16; s++) {
        if (s < nseg) { ms[s] = base[s * 2112 + 2048 + q]; M = fmaxf(M, ms[s]); }
    }
    float L = 0.f;
#pragma unroll
    for (int s = 0; s < 16; s++) {
        if (s < nseg) {
            wsg[s] = __builtin_amdgcn_exp2f(ms[s] - M);
            L += wsg[s] * base[s * 2112 + 2080 + q];
        }
    }
    float inv = 1.0f / L;
    float res[8];
#pragma unroll
    for (int i = 0; i < 8; i++) res[i] = 0.f;
#pragma unroll
    for (int s = 0; s < 16; s++) {
        if (s < nseg) {
            const float* po = base + s * 2112;
#pragma unroll
            for (int i = 0; i < 8; i++) res[i] += wsg[s] * po[(dv0 + i) * 32 + q];
        }
    }
    float* op = out + ((size_t)bt * SEQ + j * 128 + w * 32 + q) * 64 + dv0;
    float4 f0 = {res[0] * inv, res[1] * inv, res[2] * inv, res[3] * inv};
    float4 f1 = {res[4] * inv, res[5] * inv, res[6] * inv, res[7] * inv};
    *(float4*)op = f0;
    *(float4*)(op + 4) = f1;
}

// ---------------------------------------------------------------------------
extern "C" void kernel_launch(void* const* d_in, const int* in_sizes, int n_in,
                              void* d_out, int out_size, void* d_ws, size_t ws_size,
                              hipStream_t stream) {
    const float* x  = (const float*)d_in[0];
    const float* Wq = (const float*)d_in[1];
    const float* Wk = (const float*)d_in[2];
    const float* Wv = (const float*)d_in[3];
    float* out = (float*)d_out;

    char* ws = (char*)d_ws;
    short* Wb = (short*)ws;                                   // 384 KB
    short* Qs = (short*)(ws + 393216);                        // 2 MB
    short* Ks = (short*)(ws + 393216 + 2097152);              // 2 MB
    short* Vt = (short*)(ws + 393216 + 2 * 2097152);          // 2 MB  [B][64][S]
    float* pP = (float*)(ws + 6684672);                       // partials ~69 MB

    k_convw<<<dim3(192),  dim3(256), 0, stream>>>(Wq, Wk, Wv, Wb);
    k_proj <<<dim3(512),  dim3(512), 0, stream>>>(x, Wb, Qs, Ks, Vt);
    k_attn <<<dim3(1088), dim3(256), 0, stream>>>(Qs, Ks, Vt, pP);
    k_comb <<<dim3(512),  dim3(256), 0, stream>>>(pP, out);
}